// Round 2
// baseline (1019.325 us; speedup 1.0000x reference)
//
#include <hip/hip_runtime.h>

#define DIM 64
#define SCAN_CHUNK 1024

// ---------------- CSR build ----------------

__global__ void zero_int_kernel(int* __restrict__ p, int n) {
    int i = blockIdx.x * blockDim.x + threadIdx.x;
    if (i < n) p[i] = 0;
}

__global__ void deg_kernel(const int* __restrict__ dst, int* __restrict__ deg, int n_edges) {
    int e = blockIdx.x * blockDim.x + threadIdx.x;
    if (e < n_edges) atomicAdd(&deg[dst[e]], 1);
}

// pass 1: per-block (1024-element chunk) sums
__global__ void bsum_kernel(const int* __restrict__ deg, int* __restrict__ bsum, int n) {
    int t = threadIdx.x;                      // 256 threads
    int base = blockIdx.x * SCAN_CHUNK;
    int s = 0;
    #pragma unroll
    for (int k = 0; k < 4; ++k) {
        int i = base + t + k * 256;
        if (i < n) s += deg[i];
    }
    __shared__ int red[4];
    #pragma unroll
    for (int off = 32; off > 0; off >>= 1) s += __shfl_down(s, off);
    if ((t & 63) == 0) red[t >> 6] = s;
    __syncthreads();
    if (t == 0) bsum[blockIdx.x] = red[0] + red[1] + red[2] + red[3];
}

// pass 2: one block scans the (<=256) block sums, exclusive in-place; writes row_ofs[n]=total
__global__ void bscan_kernel(int* __restrict__ bsum, int nb, int* __restrict__ row_ofs, int n) {
    __shared__ int lds[256];
    int t = threadIdx.x;
    int v = (t < nb) ? bsum[t] : 0;
    lds[t] = v;
    __syncthreads();
    #pragma unroll
    for (int off = 1; off < 256; off <<= 1) {
        int u = (t >= off) ? lds[t - off] : 0;
        __syncthreads();
        lds[t] += u;
        __syncthreads();
    }
    if (t < nb) bsum[t] = lds[t] - v;          // exclusive
    if (t == nb - 1) row_ofs[n] = lds[t];      // grand total = E
}

// pass 3: per-chunk exclusive scan with chunk base
__global__ void chunk_scan_kernel(const int* __restrict__ deg, const int* __restrict__ bsum,
                                  int* __restrict__ row_ofs, int n) {
    __shared__ int lds[256];
    int t = threadIdx.x;
    int base = blockIdx.x * SCAN_CHUNK + t * 4;
    int v[4];
    int s = 0;
    #pragma unroll
    for (int k = 0; k < 4; ++k) {
        int i = base + k;
        v[k] = (i < n) ? deg[i] : 0;
        s += v[k];
    }
    lds[t] = s;
    __syncthreads();
    #pragma unroll
    for (int off = 1; off < 256; off <<= 1) {
        int u = (t >= off) ? lds[t - off] : 0;
        __syncthreads();
        lds[t] += u;
        __syncthreads();
    }
    int excl = lds[t] - s + bsum[blockIdx.x];
    #pragma unroll
    for (int k = 0; k < 4; ++k) {
        int i = base + k;
        if (i < n) row_ofs[i] = excl;
        excl += v[k];
    }
}

__global__ void aux_kernel(const int* __restrict__ deg, const int* __restrict__ row_ofs,
                           int* __restrict__ cursor, float* __restrict__ inv_deg, int n) {
    int i = blockIdx.x * blockDim.x + threadIdx.x;
    if (i < n) {
        cursor[i] = row_ofs[i];
        inv_deg[i] = 1.0f / fmaxf((float)deg[i], 1.0f);
    }
}

__global__ void fill_kernel(const int* __restrict__ src, const int* __restrict__ dst,
                            int* __restrict__ cursor, int* __restrict__ csr_src, int n_edges) {
    int e = blockIdx.x * blockDim.x + threadIdx.x;
    if (e < n_edges) {
        int d = dst[e];
        int pos = atomicAdd(&cursor[d], 1);
        csr_src[pos] = src[e];
    }
}

// ---------------- fused layer: mean-aggregate + dual transform ----------------
// One wave per node (grid-stride). Lane l owns output column l; weight columns
// Wl[:,l], Wr[:,l] stationary in VGPRs; node rows broadcast via v_readlane.
__global__ __launch_bounds__(256) void layer_kernel(
    const float* __restrict__ h, const int* __restrict__ row_ofs,
    const int* __restrict__ csr, const float* __restrict__ invd,
    const float* __restrict__ Wl, const float* __restrict__ Wr,
    const float* __restrict__ bias, float* __restrict__ out,
    int n, int resid, int relu) {
    const int lane = threadIdx.x & 63;

    float wl[DIM], wr[DIM];
    #pragma unroll
    for (int d = 0; d < DIM; ++d) {
        wl[d] = Wl[d * DIM + lane];
        wr[d] = Wr[d * DIM + lane];
    }
    const float bv = bias[lane];

    const int wave0 = __builtin_amdgcn_readfirstlane((blockIdx.x * blockDim.x + threadIdx.x) >> 6);
    const int nwaves = (gridDim.x * blockDim.x) >> 6;

    for (int nid = wave0; nid < n; nid += nwaves) {
        const int s = row_ofs[nid];
        const int e = row_ofs[nid + 1];
        float a0 = 0.f, a1 = 0.f, a2 = 0.f, a3 = 0.f;
        int j = s;
        for (; j + 3 < e; j += 4) {
            int i0 = csr[j], i1 = csr[j + 1], i2 = csr[j + 2], i3 = csr[j + 3];
            a0 += h[(size_t)i0 * DIM + lane];
            a1 += h[(size_t)i1 * DIM + lane];
            a2 += h[(size_t)i2 * DIM + lane];
            a3 += h[(size_t)i3 * DIM + lane];
        }
        for (; j < e; ++j) a0 += h[(size_t)csr[j] * DIM + lane];
        const float av = ((a0 + a1) + (a2 + a3)) * invd[nid];
        const float hv = h[(size_t)nid * DIM + lane];

        float o0 = bv, o1 = 0.f, o2 = 0.f, o3 = 0.f;
        #pragma unroll
        for (int d = 0; d < DIM; d += 2) {
            float ad0 = __int_as_float(__builtin_amdgcn_readlane(__float_as_int(av), d));
            float hd0 = __int_as_float(__builtin_amdgcn_readlane(__float_as_int(hv), d));
            float ad1 = __int_as_float(__builtin_amdgcn_readlane(__float_as_int(av), d + 1));
            float hd1 = __int_as_float(__builtin_amdgcn_readlane(__float_as_int(hv), d + 1));
            o0 += ad0 * wl[d];
            o1 += hd0 * wr[d];
            o2 += ad1 * wl[d + 1];
            o3 += hd1 * wr[d + 1];
        }
        float o = (o0 + o2) + (o1 + o3);
        if (resid) o += hv;
        if (relu) o = fmaxf(o, 0.f);
        out[(size_t)nid * DIM + lane] = o;
    }
}

// ---------------- launch ----------------

extern "C" void kernel_launch(void* const* d_in, const int* in_sizes, int n_in,
                              void* d_out, int out_size, void* d_ws, size_t ws_size,
                              hipStream_t stream) {
    const float* x  = (const float*)d_in[0];
    const int*   ei = (const int*)d_in[1];
    const float* Wl = (const float*)d_in[2];
    const float* Wr = (const float*)d_in[3];
    const float* b  = (const float*)d_in[4];

    int N = in_sizes[0] / DIM;
    int E = in_sizes[1] / 2;
    int L = in_sizes[2] / (DIM * DIM);
    const int* src = ei;
    const int* dst = ei + E;

    char* w = (char*)d_ws;
    size_t o = 0;
    auto carve = [&](size_t bytes) {
        void* p = w + o;
        o = (o + bytes + 255) & ~(size_t)255;
        return p;
    };
    float* hA      = (float*)carve((size_t)N * DIM * 4);
    float* hB      = (float*)carve((size_t)N * DIM * 4);
    int*   deg     = (int*)carve((size_t)N * 4);
    int*   row_ofs = (int*)carve((size_t)(N + 1) * 4);
    int*   cursor  = (int*)carve((size_t)N * 4);
    float* invd    = (float*)carve((size_t)N * 4);
    int*   csr     = (int*)carve((size_t)E * 4);
    int    nb      = (N + SCAN_CHUNK - 1) / SCAN_CHUNK;   // 98 for N=100k (must be <=256)
    int*   bsum    = (int*)carve((size_t)nb * 4);

    // CSR build (every call; d_ws is re-poisoned between calls)
    zero_int_kernel<<<(N + 255) / 256, 256, 0, stream>>>(deg, N);
    deg_kernel<<<(E + 255) / 256, 256, 0, stream>>>(dst, deg, E);
    bsum_kernel<<<nb, 256, 0, stream>>>(deg, bsum, N);
    bscan_kernel<<<1, 256, 0, stream>>>(bsum, nb, row_ofs, N);
    chunk_scan_kernel<<<nb, 256, 0, stream>>>(deg, bsum, row_ofs, N);
    aux_kernel<<<(N + 255) / 256, 256, 0, stream>>>(deg, row_ofs, cursor, invd, N);
    fill_kernel<<<(E + 255) / 256, 256, 0, stream>>>(src, dst, cursor, csr, E);

    const float* hcur = x;
    float* buf[2] = {hA, hB};
    int pp = 0;
    for (int i = 0; i < L; ++i) {
        int relu  = (i < L - 1) ? 1 : 0;
        int resid = (i > 0 && i < L - 1) ? 1 : 0;
        float* outp = (i == L - 1) ? (float*)d_out : buf[pp];
        layer_kernel<<<1024, 256, 0, stream>>>(
            hcur, row_ofs, csr, invd,
            Wl + (size_t)i * DIM * DIM, Wr + (size_t)i * DIM * DIM,
            b + (size_t)i * DIM, outp, N, resid, relu);
        hcur = outp;
        pp ^= 1;
    }
}

// Round 6
// 801.315 us; speedup vs baseline: 1.2721x; 1.2721x over previous
//
#include <hip/hip_runtime.h>

#define DIM 64
#define SCAN_CHUNK 1024

// ---------------- CSR build ----------------

__global__ void zero_int_kernel(int* __restrict__ p, int n) {
    int i = blockIdx.x * blockDim.x + threadIdx.x;
    if (i < n) p[i] = 0;
}

__global__ void deg_kernel(const int* __restrict__ dst, int* __restrict__ deg, int n_edges) {
    int i = blockIdx.x * blockDim.x + threadIdx.x;
    int e0 = i * 4;
    if (e0 + 3 < n_edges) {
        int4 d4 = *(const int4*)(dst + e0);
        atomicAdd(&deg[d4.x], 1);
        atomicAdd(&deg[d4.y], 1);
        atomicAdd(&deg[d4.z], 1);
        atomicAdd(&deg[d4.w], 1);
    } else {
        for (int e = e0; e < n_edges; ++e) atomicAdd(&deg[dst[e]], 1);
    }
}

// pass 1: per-1024-chunk sums
__global__ void bsum_kernel(const int* __restrict__ deg, int* __restrict__ bsum, int n) {
    int t = threadIdx.x;                      // 256 threads
    int base = blockIdx.x * SCAN_CHUNK;
    int s = 0;
    #pragma unroll
    for (int k = 0; k < 4; ++k) {
        int i = base + t + k * 256;
        if (i < n) s += deg[i];
    }
    __shared__ int red[4];
    #pragma unroll
    for (int off = 32; off > 0; off >>= 1) s += __shfl_down(s, off);
    if ((t & 63) == 0) red[t >> 6] = s;
    __syncthreads();
    if (t == 0) bsum[blockIdx.x] = red[0] + red[1] + red[2] + red[3];
}

// pass 2: one block scans the (<=256) chunk sums, exclusive in-place; row_ofs[n]=total
__global__ void bscan_kernel(int* __restrict__ bsum, int nb, int* __restrict__ row_ofs, int n) {
    __shared__ int lds[256];
    int t = threadIdx.x;
    int v = (t < nb) ? bsum[t] : 0;
    lds[t] = v;
    __syncthreads();
    #pragma unroll
    for (int off = 1; off < 256; off <<= 1) {
        int u = (t >= off) ? lds[t - off] : 0;
        __syncthreads();
        lds[t] += u;
        __syncthreads();
    }
    if (t < nb) bsum[t] = lds[t] - v;          // exclusive
    if (t == nb - 1) row_ofs[n] = lds[t];      // grand total = E
}

// pass 3: per-chunk exclusive scan + chunk base; also emits cursor & inv_deg
// (aux pass fused here: saves one dispatch and one full re-read of deg).
__global__ void chunk_scan_kernel(const int* __restrict__ deg, const int* __restrict__ bsum,
                                  int* __restrict__ row_ofs, int* __restrict__ cursor,
                                  float* __restrict__ inv_deg, int n) {
    __shared__ int lds[256];
    int t = threadIdx.x;
    int base = blockIdx.x * SCAN_CHUNK + t * 4;
    int v[4];
    int s = 0;
    #pragma unroll
    for (int k = 0; k < 4; ++k) {
        int i = base + k;
        v[k] = (i < n) ? deg[i] : 0;
        s += v[k];
    }
    lds[t] = s;
    __syncthreads();
    #pragma unroll
    for (int off = 1; off < 256; off <<= 1) {
        int u = (t >= off) ? lds[t - off] : 0;
        __syncthreads();
        lds[t] += u;
        __syncthreads();
    }
    int excl = lds[t] - s + bsum[blockIdx.x];
    #pragma unroll
    for (int k = 0; k < 4; ++k) {
        int i = base + k;
        if (i < n) {
            row_ofs[i] = excl;
            cursor[i]  = excl;
            inv_deg[i] = 1.0f / fmaxf((float)v[k], 1.0f);
        }
        excl += v[k];
    }
}

__global__ void fill_kernel(const int* __restrict__ src, const int* __restrict__ dst,
                            int* __restrict__ cursor, int* __restrict__ csr_src, int n_edges) {
    int i = blockIdx.x * blockDim.x + threadIdx.x;
    int e0 = i * 4;
    if (e0 + 3 < n_edges) {
        int4 s4 = *(const int4*)(src + e0);
        int4 d4 = *(const int4*)(dst + e0);
        csr_src[atomicAdd(&cursor[d4.x], 1)] = s4.x;
        csr_src[atomicAdd(&cursor[d4.y], 1)] = s4.y;
        csr_src[atomicAdd(&cursor[d4.z], 1)] = s4.z;
        csr_src[atomicAdd(&cursor[d4.w], 1)] = s4.w;
    } else {
        for (int e = e0; e < n_edges; ++e)
            csr_src[atomicAdd(&cursor[dst[e]], 1)] = src[e];
    }
}

// ---------------- mean aggregation, variant 1 (control) ----------------
// One wave per node. One coalesced index load per <=64 neighbors; readlane
// broadcasts; one dword gather per neighbor row; 8 accumulators for ILP.
__global__ __launch_bounds__(256) void agg_kernel_v1(
    const float* __restrict__ h, const int* __restrict__ row_ofs,
    const int* __restrict__ csr, const float* __restrict__ invd,
    float* __restrict__ agg, int n) {
    const int lane = threadIdx.x & 63;
    const int nw = (gridDim.x * blockDim.x) >> 6;
    int wave0 = (blockIdx.x * blockDim.x + threadIdx.x) >> 6;

    for (int nid = wave0; nid < n; nid += nw) {
        const int s = __builtin_amdgcn_readfirstlane(row_ofs[nid]);
        const int e = __builtin_amdgcn_readfirstlane(row_ofs[nid + 1]);
        const float iv = invd[nid];
        float a0 = 0.f, a1 = 0.f, a2 = 0.f, a3 = 0.f;
        float a4 = 0.f, a5 = 0.f, a6 = 0.f, a7 = 0.f;
        for (int c = s; c < e; c += 64) {
            int rem = e - c;
            int cnt = rem < 64 ? rem : 64;
            int vi = (lane < cnt) ? csr[c + lane] : 0;
            int t = 0;
            for (; t + 8 <= cnt; t += 8) {
                int i0 = __builtin_amdgcn_readlane(vi, t);
                int i1 = __builtin_amdgcn_readlane(vi, t + 1);
                int i2 = __builtin_amdgcn_readlane(vi, t + 2);
                int i3 = __builtin_amdgcn_readlane(vi, t + 3);
                int i4 = __builtin_amdgcn_readlane(vi, t + 4);
                int i5 = __builtin_amdgcn_readlane(vi, t + 5);
                int i6 = __builtin_amdgcn_readlane(vi, t + 6);
                int i7 = __builtin_amdgcn_readlane(vi, t + 7);
                a0 += h[(size_t)i0 * DIM + lane];
                a1 += h[(size_t)i1 * DIM + lane];
                a2 += h[(size_t)i2 * DIM + lane];
                a3 += h[(size_t)i3 * DIM + lane];
                a4 += h[(size_t)i4 * DIM + lane];
                a5 += h[(size_t)i5 * DIM + lane];
                a6 += h[(size_t)i6 * DIM + lane];
                a7 += h[(size_t)i7 * DIM + lane];
            }
            for (; t + 4 <= cnt; t += 4) {
                int i0 = __builtin_amdgcn_readlane(vi, t);
                int i1 = __builtin_amdgcn_readlane(vi, t + 1);
                int i2 = __builtin_amdgcn_readlane(vi, t + 2);
                int i3 = __builtin_amdgcn_readlane(vi, t + 3);
                a0 += h[(size_t)i0 * DIM + lane];
                a1 += h[(size_t)i1 * DIM + lane];
                a2 += h[(size_t)i2 * DIM + lane];
                a3 += h[(size_t)i3 * DIM + lane];
            }
            for (; t < cnt; ++t)
                a0 += h[(size_t)__builtin_amdgcn_readlane(vi, t) * DIM + lane];
        }
        float r = ((a0 + a1) + (a2 + a3)) + ((a4 + a5) + (a6 + a7));
        agg[(size_t)nid * DIM + lane] = r * iv;
    }
}

// ---------------- mean aggregation, variant 2 (float4 gather A/B) ----------------
// One wave per node. Lane group g=lane>>4 takes neighbor t+g; lane q=lane&15
// owns dims 4q..4q+3. One float4 load covers 4 neighbor rows (1KB/wave-load,
// 4x fewer memory requests, same bytes). Cross-group shfl_xor reduce per node.
__global__ __launch_bounds__(256) void agg_kernel_v2(
    const float* __restrict__ h, const int* __restrict__ row_ofs,
    const int* __restrict__ csr, const float* __restrict__ invd,
    float* __restrict__ agg, int n) {
    const int lane = threadIdx.x & 63;
    const int g = lane >> 4;      // neighbor subgroup 0..3
    const int q = lane & 15;      // dim quad: dims 4q..4q+3
    const int nw = (gridDim.x * blockDim.x) >> 6;
    int wave0 = (blockIdx.x * blockDim.x + threadIdx.x) >> 6;

    for (int nid = wave0; nid < n; nid += nw) {
        const int s = __builtin_amdgcn_readfirstlane(row_ofs[nid]);
        const int e = __builtin_amdgcn_readfirstlane(row_ofs[nid + 1]);
        float4 acc0 = make_float4(0.f, 0.f, 0.f, 0.f);
        float4 acc1 = make_float4(0.f, 0.f, 0.f, 0.f);
        for (int c = s; c < e; c += 64) {
            int rem = e - c;
            int cnt = rem < 64 ? rem : 64;
            int vi = (lane < cnt) ? csr[c + lane] : 0;
            for (int t = 0; t < cnt; t += 8) {
                int r0 = t + g;
                int r1 = t + 4 + g;
                int cl = cnt - 1;
                int i0 = __shfl(vi, r0 < cl ? r0 : cl);
                int i1 = __shfl(vi, r1 < cl ? r1 : cl);
                float4 v0 = *(const float4*)(h + (size_t)i0 * DIM + q * 4);
                float4 v1 = *(const float4*)(h + (size_t)i1 * DIM + q * 4);
                float f0 = (r0 < cnt) ? 1.f : 0.f;
                float f1 = (r1 < cnt) ? 1.f : 0.f;
                acc0.x = fmaf(v0.x, f0, acc0.x);
                acc0.y = fmaf(v0.y, f0, acc0.y);
                acc0.z = fmaf(v0.z, f0, acc0.z);
                acc0.w = fmaf(v0.w, f0, acc0.w);
                acc1.x = fmaf(v1.x, f1, acc1.x);
                acc1.y = fmaf(v1.y, f1, acc1.y);
                acc1.z = fmaf(v1.z, f1, acc1.z);
                acc1.w = fmaf(v1.w, f1, acc1.w);
            }
        }
        float4 r;
        r.x = acc0.x + acc1.x;
        r.y = acc0.y + acc1.y;
        r.z = acc0.z + acc1.z;
        r.w = acc0.w + acc1.w;
        // reduce across the 4 lane groups (lanes q, q+16, q+32, q+48)
        r.x += __shfl_xor(r.x, 16);
        r.y += __shfl_xor(r.y, 16);
        r.z += __shfl_xor(r.z, 16);
        r.w += __shfl_xor(r.w, 16);
        r.x += __shfl_xor(r.x, 32);
        r.y += __shfl_xor(r.y, 32);
        r.z += __shfl_xor(r.z, 32);
        r.w += __shfl_xor(r.w, 32);
        const float iv = invd[nid];
        if (lane < 16) {
            float4 o = make_float4(r.x * iv, r.y * iv, r.z * iv, r.w * iv);
            *(float4*)(agg + (size_t)nid * DIM + q * 4) = o;
        }
    }
}

// ---------------- dual transform ----------------
// out[n][l] = b[l] + sum_d agg[n][d]*Wl[d][l] + sum_d h[n][d]*Wr[d][l] (+h[n][l]) (+relu)
// launch_bounds(256,1): VGPR budget up to 512 so the 128 weight values stay
// register-resident across the whole node loop (round-2 showed VGPR=72 ->
// compiler was reloading 32KB of weights per node).
__global__ __launch_bounds__(256, 1) void transform_kernel(
    const float* __restrict__ agg, const float* __restrict__ h,
    const float* __restrict__ Wl, const float* __restrict__ Wr,
    const float* __restrict__ bias, float* __restrict__ out,
    int n, int resid, int relu) {
    const int lane = threadIdx.x & 63;

    float wl[DIM], wr[DIM];
    #pragma unroll
    for (int d = 0; d < DIM; ++d) {
        wl[d] = Wl[d * DIM + lane];
        wr[d] = Wr[d * DIM + lane];
    }
    const float bv = bias[lane];

    const int nw = (gridDim.x * blockDim.x) >> 6;
    int nid = (blockIdx.x * blockDim.x + threadIdx.x) >> 6;
    if (nid >= n) return;

    float av = agg[(size_t)nid * DIM + lane];
    float hv = h[(size_t)nid * DIM + lane];

    while (true) {
        int nxt = nid + nw;
        float avn = 0.f, hvn = 0.f;
        if (nxt < n) {                       // prefetch next node's rows
            avn = agg[(size_t)nxt * DIM + lane];
            hvn = h[(size_t)nxt * DIM + lane];
        }
        float o0 = bv, o1 = 0.f, o2 = 0.f, o3 = 0.f;
        #pragma unroll
        for (int d = 0; d < DIM; d += 2) {
            float ad0 = __int_as_float(__builtin_amdgcn_readlane(__float_as_int(av), d));
            float hd0 = __int_as_float(__builtin_amdgcn_readlane(__float_as_int(hv), d));
            float ad1 = __int_as_float(__builtin_amdgcn_readlane(__float_as_int(av), d + 1));
            float hd1 = __int_as_float(__builtin_amdgcn_readlane(__float_as_int(hv), d + 1));
            o0 += ad0 * wl[d];
            o1 += hd0 * wr[d];
            o2 += ad1 * wl[d + 1];
            o3 += hd1 * wr[d + 1];
        }
        float o = (o0 + o2) + (o1 + o3);
        if (resid) o += hv;
        if (relu) o = fmaxf(o, 0.f);
        out[(size_t)nid * DIM + lane] = o;
        if (nxt >= n) break;
        nid = nxt;
        av = avn;
        hv = hvn;
    }
}

// ---------------- launch ----------------

extern "C" void kernel_launch(void* const* d_in, const int* in_sizes, int n_in,
                              void* d_out, int out_size, void* d_ws, size_t ws_size,
                              hipStream_t stream) {
    const float* x  = (const float*)d_in[0];
    const int*   ei = (const int*)d_in[1];
    const float* Wl = (const float*)d_in[2];
    const float* Wr = (const float*)d_in[3];
    const float* b  = (const float*)d_in[4];

    int N = in_sizes[0] / DIM;
    int E = in_sizes[1] / 2;
    int L = in_sizes[2] / (DIM * DIM);
    const int* src = ei;
    const int* dst = ei + E;
    float* out_f = (float*)d_out;

    char* w = (char*)d_ws;
    size_t o = 0;
    auto carve = [&](size_t bytes) {
        void* p = w + o;
        o = (o + bytes + 255) & ~(size_t)255;
        return p;
    };
    float* aggb    = (float*)carve((size_t)N * DIM * 4);   // aggregation buffer
    float* hB      = (float*)carve((size_t)N * DIM * 4);   // ping-pong with d_out
    int*   deg     = (int*)carve((size_t)N * 4);
    int*   row_ofs = (int*)carve((size_t)(N + 1) * 4);
    int*   cursor  = (int*)carve((size_t)N * 4);
    float* invd    = (float*)carve((size_t)N * 4);
    int*   csr     = (int*)carve((size_t)E * 4);
    int    nb      = (N + SCAN_CHUNK - 1) / SCAN_CHUNK;    // 98 for N=100k (<=256 req)
    int*   bsum    = (int*)carve((size_t)nb * 4);

    // CSR build (every call; d_ws is re-poisoned between calls)
    zero_int_kernel<<<(N + 255) / 256, 256, 0, stream>>>(deg, N);
    deg_kernel<<<(E / 4 + 255) / 256, 256, 0, stream>>>(dst, deg, E);
    bsum_kernel<<<nb, 256, 0, stream>>>(deg, bsum, N);
    bscan_kernel<<<1, 256, 0, stream>>>(bsum, nb, row_ofs, N);
    chunk_scan_kernel<<<nb, 256, 0, stream>>>(deg, bsum, row_ofs, cursor, invd, N);
    fill_kernel<<<(E / 4 + 255) / 256, 256, 0, stream>>>(src, dst, cursor, csr, E);

    const float* hcur = x;
    for (int i = 0; i < L; ++i) {
        // Within-probe A/B: even layers run v1 (control), odd layers v2 (float4).
        if (i & 1)
            agg_kernel_v2<<<4096, 256, 0, stream>>>(hcur, row_ofs, csr, invd, aggb, N);
        else
            agg_kernel_v1<<<4096, 256, 0, stream>>>(hcur, row_ofs, csr, invd, aggb, N);

        int relu  = (i < L - 1) ? 1 : 0;
        int resid = (i > 0 && i < L - 1) ? 1 : 0;
        float* outp;
        if (i == L - 1) {
            outp = (hcur != out_f) ? out_f : hB;   // final layer -> d_out if safe
        } else {
            outp = (hcur == out_f) ? hB : out_f;   // ping-pong, never in-place
        }
        transform_kernel<<<1024, 256, 0, stream>>>(
            aggb, hcur, Wl + (size_t)i * DIM * DIM, Wr + (size_t)i * DIM * DIM,
            b + (size_t)i * DIM, outp, N, resid, relu);

        if (i == L - 1 && outp != out_f)           // generic-L safety net
            hipMemcpyAsync(out_f, outp, (size_t)N * DIM * 4,
                           hipMemcpyDeviceToDevice, stream);
        hcur = outp;
    }
}

// Round 9
// 797.696 us; speedup vs baseline: 1.2778x; 1.0045x over previous
//
#include <hip/hip_runtime.h>

#define DIM 64
#define SCAN_CHUNK 1024

// ---------------- CSR build ----------------

__global__ void zero_int_kernel(int* __restrict__ p, int n) {
    int i = blockIdx.x * blockDim.x + threadIdx.x;
    if (i < n) p[i] = 0;
}

// 8 edges/thread, vectorized loads, fire-and-forget atomics.
__global__ void deg_kernel(const int* __restrict__ dst, int* __restrict__ deg, int n_edges) {
    int i = blockIdx.x * blockDim.x + threadIdx.x;
    int e0 = i * 8;
    if (e0 + 7 < n_edges) {
        int4 a = *(const int4*)(dst + e0);
        int4 b = *(const int4*)(dst + e0 + 4);
        atomicAdd(&deg[a.x], 1);
        atomicAdd(&deg[a.y], 1);
        atomicAdd(&deg[a.z], 1);
        atomicAdd(&deg[a.w], 1);
        atomicAdd(&deg[b.x], 1);
        atomicAdd(&deg[b.y], 1);
        atomicAdd(&deg[b.z], 1);
        atomicAdd(&deg[b.w], 1);
    } else {
        for (int e = e0; e < n_edges; ++e) atomicAdd(&deg[dst[e]], 1);
    }
}

// pass 1: per-1024-chunk sums
__global__ void bsum_kernel(const int* __restrict__ deg, int* __restrict__ bsum, int n) {
    int t = threadIdx.x;                      // 256 threads
    int base = blockIdx.x * SCAN_CHUNK;
    int s = 0;
    #pragma unroll
    for (int k = 0; k < 4; ++k) {
        int i = base + t + k * 256;
        if (i < n) s += deg[i];
    }
    __shared__ int red[4];
    #pragma unroll
    for (int off = 32; off > 0; off >>= 1) s += __shfl_down(s, off);
    if ((t & 63) == 0) red[t >> 6] = s;
    __syncthreads();
    if (t == 0) bsum[blockIdx.x] = red[0] + red[1] + red[2] + red[3];
}

// pass 2: one block scans the (<=256) chunk sums, exclusive in-place; row_ofs[n]=total
__global__ void bscan_kernel(int* __restrict__ bsum, int nb, int* __restrict__ row_ofs, int n) {
    __shared__ int lds[256];
    int t = threadIdx.x;
    int v = (t < nb) ? bsum[t] : 0;
    lds[t] = v;
    __syncthreads();
    #pragma unroll
    for (int off = 1; off < 256; off <<= 1) {
        int u = (t >= off) ? lds[t - off] : 0;
        __syncthreads();
        lds[t] += u;
        __syncthreads();
    }
    if (t < nb) bsum[t] = lds[t] - v;          // exclusive
    if (t == nb - 1) row_ofs[n] = lds[t];      // grand total = E
}

// pass 3: per-chunk exclusive scan + chunk base; also emits cursor & inv_deg.
__global__ void chunk_scan_kernel(const int* __restrict__ deg, const int* __restrict__ bsum,
                                  int* __restrict__ row_ofs, int* __restrict__ cursor,
                                  float* __restrict__ inv_deg, int n) {
    __shared__ int lds[256];
    int t = threadIdx.x;
    int base = blockIdx.x * SCAN_CHUNK + t * 4;
    int v[4];
    int s = 0;
    #pragma unroll
    for (int k = 0; k < 4; ++k) {
        int i = base + k;
        v[k] = (i < n) ? deg[i] : 0;
        s += v[k];
    }
    lds[t] = s;
    __syncthreads();
    #pragma unroll
    for (int off = 1; off < 256; off <<= 1) {
        int u = (t >= off) ? lds[t - off] : 0;
        __syncthreads();
        lds[t] += u;
        __syncthreads();
    }
    int excl = lds[t] - s + bsum[blockIdx.x];
    #pragma unroll
    for (int k = 0; k < 4; ++k) {
        int i = base + k;
        if (i < n) {
            row_ofs[i] = excl;
            cursor[i]  = excl;
            inv_deg[i] = 1.0f / fmaxf((float)v[k], 1.0f);
        }
        excl += v[k];
    }
}

// 8 edges/thread; nontemporal SCALAR scatter stores (no-allocate: targets the
// 17x write amplification from 64B-line ping-pong between non-coherent XCD
// L2s seen in round 6: WRITE_SIZE=108MB for 6.4MB of payload).
// NOTE: __builtin_nontemporal_load rejects HIP_vector_type (int4) pointers --
// plain int4 loads here; nt only on the scalar int stores (accepted types).
__global__ void fill_kernel(const int* __restrict__ src, const int* __restrict__ dst,
                            int* __restrict__ cursor, int* __restrict__ csr_src, int n_edges) {
    int i = blockIdx.x * blockDim.x + threadIdx.x;
    int e0 = i * 8;
    if (e0 + 7 < n_edges) {
        int4 sa = *(const int4*)(src + e0);
        int4 da = *(const int4*)(dst + e0);
        int4 sb = *(const int4*)(src + e0 + 4);
        int4 db = *(const int4*)(dst + e0 + 4);
        int p0 = atomicAdd(&cursor[da.x], 1);
        int p1 = atomicAdd(&cursor[da.y], 1);
        int p2 = atomicAdd(&cursor[da.z], 1);
        int p3 = atomicAdd(&cursor[da.w], 1);
        int p4 = atomicAdd(&cursor[db.x], 1);
        int p5 = atomicAdd(&cursor[db.y], 1);
        int p6 = atomicAdd(&cursor[db.z], 1);
        int p7 = atomicAdd(&cursor[db.w], 1);
        __builtin_nontemporal_store(sa.x, &csr_src[p0]);
        __builtin_nontemporal_store(sa.y, &csr_src[p1]);
        __builtin_nontemporal_store(sa.z, &csr_src[p2]);
        __builtin_nontemporal_store(sa.w, &csr_src[p3]);
        __builtin_nontemporal_store(sb.x, &csr_src[p4]);
        __builtin_nontemporal_store(sb.y, &csr_src[p5]);
        __builtin_nontemporal_store(sb.z, &csr_src[p6]);
        __builtin_nontemporal_store(sb.w, &csr_src[p7]);
    } else {
        for (int e = e0; e < n_edges; ++e)
            csr_src[atomicAdd(&cursor[dst[e]], 1)] = src[e];
    }
}

// ---------------- mean aggregation, variant 1 (control) ----------------
// One wave per node. One coalesced index load per <=64 neighbors; readlane
// broadcasts; one dword gather per neighbor row; 8 accumulators for ILP.
__global__ __launch_bounds__(256) void agg_kernel_v1(
    const float* __restrict__ h, const int* __restrict__ row_ofs,
    const int* __restrict__ csr, const float* __restrict__ invd,
    float* __restrict__ agg, int n) {
    const int lane = threadIdx.x & 63;
    const int nw = (gridDim.x * blockDim.x) >> 6;
    int wave0 = (blockIdx.x * blockDim.x + threadIdx.x) >> 6;

    for (int nid = wave0; nid < n; nid += nw) {
        const int s = __builtin_amdgcn_readfirstlane(row_ofs[nid]);
        const int e = __builtin_amdgcn_readfirstlane(row_ofs[nid + 1]);
        const float iv = invd[nid];
        float a0 = 0.f, a1 = 0.f, a2 = 0.f, a3 = 0.f;
        float a4 = 0.f, a5 = 0.f, a6 = 0.f, a7 = 0.f;
        for (int c = s; c < e; c += 64) {
            int rem = e - c;
            int cnt = rem < 64 ? rem : 64;
            int vi = (lane < cnt) ? csr[c + lane] : 0;
            int t = 0;
            for (; t + 8 <= cnt; t += 8) {
                int i0 = __builtin_amdgcn_readlane(vi, t);
                int i1 = __builtin_amdgcn_readlane(vi, t + 1);
                int i2 = __builtin_amdgcn_readlane(vi, t + 2);
                int i3 = __builtin_amdgcn_readlane(vi, t + 3);
                int i4 = __builtin_amdgcn_readlane(vi, t + 4);
                int i5 = __builtin_amdgcn_readlane(vi, t + 5);
                int i6 = __builtin_amdgcn_readlane(vi, t + 6);
                int i7 = __builtin_amdgcn_readlane(vi, t + 7);
                a0 += h[(size_t)i0 * DIM + lane];
                a1 += h[(size_t)i1 * DIM + lane];
                a2 += h[(size_t)i2 * DIM + lane];
                a3 += h[(size_t)i3 * DIM + lane];
                a4 += h[(size_t)i4 * DIM + lane];
                a5 += h[(size_t)i5 * DIM + lane];
                a6 += h[(size_t)i6 * DIM + lane];
                a7 += h[(size_t)i7 * DIM + lane];
            }
            for (; t + 4 <= cnt; t += 4) {
                int i0 = __builtin_amdgcn_readlane(vi, t);
                int i1 = __builtin_amdgcn_readlane(vi, t + 1);
                int i2 = __builtin_amdgcn_readlane(vi, t + 2);
                int i3 = __builtin_amdgcn_readlane(vi, t + 3);
                a0 += h[(size_t)i0 * DIM + lane];
                a1 += h[(size_t)i1 * DIM + lane];
                a2 += h[(size_t)i2 * DIM + lane];
                a3 += h[(size_t)i3 * DIM + lane];
            }
            for (; t < cnt; ++t)
                a0 += h[(size_t)__builtin_amdgcn_readlane(vi, t) * DIM + lane];
        }
        float r = ((a0 + a1) + (a2 + a3)) + ((a4 + a5) + (a6 + a7));
        agg[(size_t)nid * DIM + lane] = r * iv;
    }
}

// ---------------- mean aggregation, variant 2 (float4 gather A/B) ----------------
// One wave per node. Lane group g=lane>>4 takes neighbor t+g; lane q=lane&15
// owns dims 4q..4q+3. One float4 load covers 4 neighbor rows (1KB/wave-load,
// 4x fewer memory requests, same bytes). Cross-group shfl_xor reduce per node.
__global__ __launch_bounds__(256) void agg_kernel_v2(
    const float* __restrict__ h, const int* __restrict__ row_ofs,
    const int* __restrict__ csr, const float* __restrict__ invd,
    float* __restrict__ agg, int n) {
    const int lane = threadIdx.x & 63;
    const int g = lane >> 4;      // neighbor subgroup 0..3
    const int q = lane & 15;      // dim quad: dims 4q..4q+3
    const int nw = (gridDim.x * blockDim.x) >> 6;
    int wave0 = (blockIdx.x * blockDim.x + threadIdx.x) >> 6;

    for (int nid = wave0; nid < n; nid += nw) {
        const int s = __builtin_amdgcn_readfirstlane(row_ofs[nid]);
        const int e = __builtin_amdgcn_readfirstlane(row_ofs[nid + 1]);
        float4 acc0 = make_float4(0.f, 0.f, 0.f, 0.f);
        float4 acc1 = make_float4(0.f, 0.f, 0.f, 0.f);
        for (int c = s; c < e; c += 64) {
            int rem = e - c;
            int cnt = rem < 64 ? rem : 64;
            int vi = (lane < cnt) ? csr[c + lane] : 0;
            for (int t = 0; t < cnt; t += 8) {
                int r0 = t + g;
                int r1 = t + 4 + g;
                int cl = cnt - 1;
                int i0 = __shfl(vi, r0 < cl ? r0 : cl);
                int i1 = __shfl(vi, r1 < cl ? r1 : cl);
                float4 v0 = *(const float4*)(h + (size_t)i0 * DIM + q * 4);
                float4 v1 = *(const float4*)(h + (size_t)i1 * DIM + q * 4);
                float f0 = (r0 < cnt) ? 1.f : 0.f;
                float f1 = (r1 < cnt) ? 1.f : 0.f;
                acc0.x = fmaf(v0.x, f0, acc0.x);
                acc0.y = fmaf(v0.y, f0, acc0.y);
                acc0.z = fmaf(v0.z, f0, acc0.z);
                acc0.w = fmaf(v0.w, f0, acc0.w);
                acc1.x = fmaf(v1.x, f1, acc1.x);
                acc1.y = fmaf(v1.y, f1, acc1.y);
                acc1.z = fmaf(v1.z, f1, acc1.z);
                acc1.w = fmaf(v1.w, f1, acc1.w);
            }
        }
        float4 r;
        r.x = acc0.x + acc1.x;
        r.y = acc0.y + acc1.y;
        r.z = acc0.z + acc1.z;
        r.w = acc0.w + acc1.w;
        // reduce across the 4 lane groups (lanes q, q+16, q+32, q+48)
        r.x += __shfl_xor(r.x, 16);
        r.y += __shfl_xor(r.y, 16);
        r.z += __shfl_xor(r.z, 16);
        r.w += __shfl_xor(r.w, 16);
        r.x += __shfl_xor(r.x, 32);
        r.y += __shfl_xor(r.y, 32);
        r.z += __shfl_xor(r.z, 32);
        r.w += __shfl_xor(r.w, 32);
        const float iv = invd[nid];
        if (lane < 16) {
            float4 o = make_float4(r.x * iv, r.y * iv, r.z * iv, r.w * iv);
            *(float4*)(agg + (size_t)nid * DIM + q * 4) = o;
        }
    }
}

// ---------------- dual transform ----------------
// out[n][l] = b[l] + sum_d agg[n][d]*Wl[d][l] + sum_d h[n][d]*Wr[d][l] (+h[n][l]) (+relu)
// launch_bounds(256,1): VGPR budget up to 512 so the 128 weight values stay
// register-resident across the whole node loop (round-2 showed VGPR=72 ->
// compiler was reloading 32KB of weights per node).
__global__ __launch_bounds__(256, 1) void transform_kernel(
    const float* __restrict__ agg, const float* __restrict__ h,
    const float* __restrict__ Wl, const float* __restrict__ Wr,
    const float* __restrict__ bias, float* __restrict__ out,
    int n, int resid, int relu) {
    const int lane = threadIdx.x & 63;

    float wl[DIM], wr[DIM];
    #pragma unroll
    for (int d = 0; d < DIM; ++d) {
        wl[d] = Wl[d * DIM + lane];
        wr[d] = Wr[d * DIM + lane];
    }
    const float bv = bias[lane];

    const int nw = (gridDim.x * blockDim.x) >> 6;
    int nid = (blockIdx.x * blockDim.x + threadIdx.x) >> 6;
    if (nid >= n) return;

    float av = agg[(size_t)nid * DIM + lane];
    float hv = h[(size_t)nid * DIM + lane];

    while (true) {
        int nxt = nid + nw;
        float avn = 0.f, hvn = 0.f;
        if (nxt < n) {                       // prefetch next node's rows
            avn = agg[(size_t)nxt * DIM + lane];
            hvn = h[(size_t)nxt * DIM + lane];
        }
        float o0 = bv, o1 = 0.f, o2 = 0.f, o3 = 0.f;
        #pragma unroll
        for (int d = 0; d < DIM; d += 2) {
            float ad0 = __int_as_float(__builtin_amdgcn_readlane(__float_as_int(av), d));
            float hd0 = __int_as_float(__builtin_amdgcn_readlane(__float_as_int(hv), d));
            float ad1 = __int_as_float(__builtin_amdgcn_readlane(__float_as_int(av), d + 1));
            float hd1 = __int_as_float(__builtin_amdgcn_readlane(__float_as_int(hv), d + 1));
            o0 += ad0 * wl[d];
            o1 += hd0 * wr[d];
            o2 += ad1 * wl[d + 1];
            o3 += hd1 * wr[d + 1];
        }
        float o = (o0 + o2) + (o1 + o3);
        if (resid) o += hv;
        if (relu) o = fmaxf(o, 0.f);
        out[(size_t)nid * DIM + lane] = o;
        if (nxt >= n) break;
        nid = nxt;
        av = avn;
        hv = hvn;
    }
}

// ---------------- launch ----------------

extern "C" void kernel_launch(void* const* d_in, const int* in_sizes, int n_in,
                              void* d_out, int out_size, void* d_ws, size_t ws_size,
                              hipStream_t stream) {
    const float* x  = (const float*)d_in[0];
    const int*   ei = (const int*)d_in[1];
    const float* Wl = (const float*)d_in[2];
    const float* Wr = (const float*)d_in[3];
    const float* b  = (const float*)d_in[4];

    int N = in_sizes[0] / DIM;
    int E = in_sizes[1] / 2;
    int L = in_sizes[2] / (DIM * DIM);
    const int* src = ei;
    const int* dst = ei + E;
    float* out_f = (float*)d_out;

    char* w = (char*)d_ws;
    size_t o = 0;
    auto carve = [&](size_t bytes) {
        void* p = w + o;
        o = (o + bytes + 255) & ~(size_t)255;
        return p;
    };
    float* aggb    = (float*)carve((size_t)N * DIM * 4);   // aggregation buffer
    float* hB      = (float*)carve((size_t)N * DIM * 4);   // ping-pong with d_out
    int*   deg     = (int*)carve((size_t)N * 4);
    int*   row_ofs = (int*)carve((size_t)(N + 1) * 4);
    int*   cursor  = (int*)carve((size_t)N * 4);
    float* invd    = (float*)carve((size_t)N * 4);
    int*   csr     = (int*)carve((size_t)E * 4);
    int    nb      = (N + SCAN_CHUNK - 1) / SCAN_CHUNK;    // 98 for N=100k (<=256 req)
    int*   bsum    = (int*)carve((size_t)nb * 4);

    // CSR build (every call; d_ws is re-poisoned between calls)
    zero_int_kernel<<<(N + 255) / 256, 256, 0, stream>>>(deg, N);
    deg_kernel<<<(E / 8 + 255) / 256, 256, 0, stream>>>(dst, deg, E);
    bsum_kernel<<<nb, 256, 0, stream>>>(deg, bsum, N);
    bscan_kernel<<<1, 256, 0, stream>>>(bsum, nb, row_ofs, N);
    chunk_scan_kernel<<<nb, 256, 0, stream>>>(deg, bsum, row_ofs, cursor, invd, N);
    fill_kernel<<<(E / 8 + 255) / 256, 256, 0, stream>>>(src, dst, cursor, csr, E);

    const float* hcur = x;
    for (int i = 0; i < L; ++i) {
        // Within-probe A/B: even layers run v1 (control), odd layers v2 (float4).
        if (i & 1)
            agg_kernel_v2<<<4096, 256, 0, stream>>>(hcur, row_ofs, csr, invd, aggb, N);
        else
            agg_kernel_v1<<<4096, 256, 0, stream>>>(hcur, row_ofs, csr, invd, aggb, N);

        int relu  = (i < L - 1) ? 1 : 0;
        int resid = (i > 0 && i < L - 1) ? 1 : 0;
        float* outp;
        if (i == L - 1) {
            outp = (hcur != out_f) ? out_f : hB;   // final layer -> d_out if safe
        } else {
            outp = (hcur == out_f) ? hB : out_f;   // ping-pong, never in-place
        }
        transform_kernel<<<1024, 256, 0, stream>>>(
            aggb, hcur, Wl + (size_t)i * DIM * DIM, Wr + (size_t)i * DIM * DIM,
            b + (size_t)i * DIM, outp, N, resid, relu);

        if (i == L - 1 && outp != out_f)           // generic-L safety net
            (void)hipMemcpyAsync(out_f, outp, (size_t)N * DIM * 4,
                                 hipMemcpyDeviceToDevice, stream);
        hcur = outp;
    }
}

// Round 10
// 751.454 us; speedup vs baseline: 1.3565x; 1.0615x over previous
//
#include <hip/hip_runtime.h>

#define DIM 64
#define SCAN_CHUNK 1024
#define NSHARD 8
#define FILL_CHUNKS 512

// ---------------- CSR build ----------------

__global__ void zero_int_kernel(int* __restrict__ p, int n) {
    int i = blockIdx.x * blockDim.x + threadIdx.x;
    if (i < n) p[i] = 0;
}

// Sharded-by-dst degree count: block (blockIdx&7) only processes dst nodes in
// its shard -> deg lines for a shard are touched by one XCD's L2 (blockIdx%8
// round-robins XCDs), so atomic lines don't ping-pong across L2s. Each chunk
// of the edge list is scanned 8x (once per shard) -- L3-resident, cheap.
__global__ __launch_bounds__(256) void deg_kernel_sharded(
    const int* __restrict__ dst, int* __restrict__ deg, int n_edges, int shard_sz) {
    const int shard = blockIdx.x & (NSHARD - 1);
    const int lo = shard * shard_sz;
    const int hi = lo + shard_sz;
    const int nch = gridDim.x >> 3;
    const int ch = blockIdx.x >> 3;
    long per = ((long)n_edges + nch - 1) / nch;
    per = (per + 3) & ~3L;                       // keep int4 alignment
    const long e0 = (long)ch * per;
    const long e1 = (e0 + per < (long)n_edges) ? e0 + per : (long)n_edges;
    for (long b = e0 + (long)threadIdx.x * 4; b < e1; b += 256 * 4) {
        if (b + 3 < e1) {
            int4 d4 = *(const int4*)(dst + b);
            if (d4.x >= lo && d4.x < hi) atomicAdd(&deg[d4.x], 1);
            if (d4.y >= lo && d4.y < hi) atomicAdd(&deg[d4.y], 1);
            if (d4.z >= lo && d4.z < hi) atomicAdd(&deg[d4.z], 1);
            if (d4.w >= lo && d4.w < hi) atomicAdd(&deg[d4.w], 1);
        } else {
            for (long e = b; e < e1; ++e) {
                int d = dst[e];
                if (d >= lo && d < hi) atomicAdd(&deg[d], 1);
            }
        }
    }
}

// pass 1: per-1024-chunk sums
__global__ void bsum_kernel(const int* __restrict__ deg, int* __restrict__ bsum, int n) {
    int t = threadIdx.x;                      // 256 threads
    int base = blockIdx.x * SCAN_CHUNK;
    int s = 0;
    #pragma unroll
    for (int k = 0; k < 4; ++k) {
        int i = base + t + k * 256;
        if (i < n) s += deg[i];
    }
    __shared__ int red[4];
    #pragma unroll
    for (int off = 32; off > 0; off >>= 1) s += __shfl_down(s, off);
    if ((t & 63) == 0) red[t >> 6] = s;
    __syncthreads();
    if (t == 0) bsum[blockIdx.x] = red[0] + red[1] + red[2] + red[3];
}

// pass 2: one block scans the (<=256) chunk sums, exclusive in-place; row_ofs[n]=total
__global__ void bscan_kernel(int* __restrict__ bsum, int nb, int* __restrict__ row_ofs, int n) {
    __shared__ int lds[256];
    int t = threadIdx.x;
    int v = (t < nb) ? bsum[t] : 0;
    lds[t] = v;
    __syncthreads();
    #pragma unroll
    for (int off = 1; off < 256; off <<= 1) {
        int u = (t >= off) ? lds[t - off] : 0;
        __syncthreads();
        lds[t] += u;
        __syncthreads();
    }
    if (t < nb) bsum[t] = lds[t] - v;          // exclusive
    if (t == nb - 1) row_ofs[n] = lds[t];      // grand total = E
}

// pass 3: per-chunk exclusive scan + chunk base; also emits cursor & inv_deg.
__global__ void chunk_scan_kernel(const int* __restrict__ deg, const int* __restrict__ bsum,
                                  int* __restrict__ row_ofs, int* __restrict__ cursor,
                                  float* __restrict__ inv_deg, int n) {
    __shared__ int lds[256];
    int t = threadIdx.x;
    int base = blockIdx.x * SCAN_CHUNK + t * 4;
    int v[4];
    int s = 0;
    #pragma unroll
    for (int k = 0; k < 4; ++k) {
        int i = base + k;
        v[k] = (i < n) ? deg[i] : 0;
        s += v[k];
    }
    lds[t] = s;
    __syncthreads();
    #pragma unroll
    for (int off = 1; off < 256; off <<= 1) {
        int u = (t >= off) ? lds[t - off] : 0;
        __syncthreads();
        lds[t] += u;
        __syncthreads();
    }
    int excl = lds[t] - s + bsum[blockIdx.x];
    #pragma unroll
    for (int k = 0; k < 4; ++k) {
        int i = base + k;
        if (i < n) {
            row_ofs[i] = excl;
            cursor[i]  = excl;
            inv_deg[i] = 1.0f / fmaxf((float)v[k], 1.0f);
        }
        excl += v[k];
    }
}

// Sharded-by-dst CSR fill. Mechanism (round-9 counters): random 4B scatter =
// one 64B line writeback PER STORE (WRITE_SIZE 110MB for 6.4MB payload; nt
// stores were null). A shard's csr segment [row_ofs[lo], row_ofs[hi]) is
// contiguous and written only by blocks with blockIdx%8==shard (one XCD's L2
// under round-robin dispatch) -> 16 stores/line combine in L2, write back
// once. Plain stores (we WANT L2 allocation now). Reads are 8x-amplified but
// L3-resident.
__global__ __launch_bounds__(256) void fill_kernel_sharded(
    const int* __restrict__ src, const int* __restrict__ dst,
    int* __restrict__ cursor, int* __restrict__ csr_src, int n_edges, int shard_sz) {
    const int shard = blockIdx.x & (NSHARD - 1);
    const int lo = shard * shard_sz;
    const int hi = lo + shard_sz;
    const int nch = gridDim.x >> 3;
    const int ch = blockIdx.x >> 3;
    long per = ((long)n_edges + nch - 1) / nch;
    per = (per + 3) & ~3L;
    const long e0 = (long)ch * per;
    const long e1 = (e0 + per < (long)n_edges) ? e0 + per : (long)n_edges;
    for (long b = e0 + (long)threadIdx.x * 4; b < e1; b += 256 * 4) {
        if (b + 3 < e1) {
            int4 s4 = *(const int4*)(src + b);
            int4 d4 = *(const int4*)(dst + b);
            if (d4.x >= lo && d4.x < hi) csr_src[atomicAdd(&cursor[d4.x], 1)] = s4.x;
            if (d4.y >= lo && d4.y < hi) csr_src[atomicAdd(&cursor[d4.y], 1)] = s4.y;
            if (d4.z >= lo && d4.z < hi) csr_src[atomicAdd(&cursor[d4.z], 1)] = s4.z;
            if (d4.w >= lo && d4.w < hi) csr_src[atomicAdd(&cursor[d4.w], 1)] = s4.w;
        } else {
            for (long e = b; e < e1; ++e) {
                int d = dst[e];
                if (d >= lo && d < hi) csr_src[atomicAdd(&cursor[d], 1)] = src[e];
            }
        }
    }
}

// ---------------- mean aggregation, variant 1 (control) ----------------
// One wave per node. One coalesced index load per <=64 neighbors; readlane
// broadcasts; one dword gather per neighbor row; 8 accumulators for ILP.
__global__ __launch_bounds__(256) void agg_kernel_v1(
    const float* __restrict__ h, const int* __restrict__ row_ofs,
    const int* __restrict__ csr, const float* __restrict__ invd,
    float* __restrict__ agg, int n) {
    const int lane = threadIdx.x & 63;
    const int nw = (gridDim.x * blockDim.x) >> 6;
    int wave0 = (blockIdx.x * blockDim.x + threadIdx.x) >> 6;

    for (int nid = wave0; nid < n; nid += nw) {
        const int s = __builtin_amdgcn_readfirstlane(row_ofs[nid]);
        const int e = __builtin_amdgcn_readfirstlane(row_ofs[nid + 1]);
        const float iv = invd[nid];
        float a0 = 0.f, a1 = 0.f, a2 = 0.f, a3 = 0.f;
        float a4 = 0.f, a5 = 0.f, a6 = 0.f, a7 = 0.f;
        for (int c = s; c < e; c += 64) {
            int rem = e - c;
            int cnt = rem < 64 ? rem : 64;
            int vi = (lane < cnt) ? csr[c + lane] : 0;
            int t = 0;
            for (; t + 8 <= cnt; t += 8) {
                int i0 = __builtin_amdgcn_readlane(vi, t);
                int i1 = __builtin_amdgcn_readlane(vi, t + 1);
                int i2 = __builtin_amdgcn_readlane(vi, t + 2);
                int i3 = __builtin_amdgcn_readlane(vi, t + 3);
                int i4 = __builtin_amdgcn_readlane(vi, t + 4);
                int i5 = __builtin_amdgcn_readlane(vi, t + 5);
                int i6 = __builtin_amdgcn_readlane(vi, t + 6);
                int i7 = __builtin_amdgcn_readlane(vi, t + 7);
                a0 += h[(size_t)i0 * DIM + lane];
                a1 += h[(size_t)i1 * DIM + lane];
                a2 += h[(size_t)i2 * DIM + lane];
                a3 += h[(size_t)i3 * DIM + lane];
                a4 += h[(size_t)i4 * DIM + lane];
                a5 += h[(size_t)i5 * DIM + lane];
                a6 += h[(size_t)i6 * DIM + lane];
                a7 += h[(size_t)i7 * DIM + lane];
            }
            for (; t + 4 <= cnt; t += 4) {
                int i0 = __builtin_amdgcn_readlane(vi, t);
                int i1 = __builtin_amdgcn_readlane(vi, t + 1);
                int i2 = __builtin_amdgcn_readlane(vi, t + 2);
                int i3 = __builtin_amdgcn_readlane(vi, t + 3);
                a0 += h[(size_t)i0 * DIM + lane];
                a1 += h[(size_t)i1 * DIM + lane];
                a2 += h[(size_t)i2 * DIM + lane];
                a3 += h[(size_t)i3 * DIM + lane];
            }
            for (; t < cnt; ++t)
                a0 += h[(size_t)__builtin_amdgcn_readlane(vi, t) * DIM + lane];
        }
        float r = ((a0 + a1) + (a2 + a3)) + ((a4 + a5) + (a6 + a7));
        agg[(size_t)nid * DIM + lane] = r * iv;
    }
}

// ---------------- mean aggregation, variant 2 (float4 gather A/B) ----------------
__global__ __launch_bounds__(256) void agg_kernel_v2(
    const float* __restrict__ h, const int* __restrict__ row_ofs,
    const int* __restrict__ csr, const float* __restrict__ invd,
    float* __restrict__ agg, int n) {
    const int lane = threadIdx.x & 63;
    const int g = lane >> 4;      // neighbor subgroup 0..3
    const int q = lane & 15;      // dim quad: dims 4q..4q+3
    const int nw = (gridDim.x * blockDim.x) >> 6;
    int wave0 = (blockIdx.x * blockDim.x + threadIdx.x) >> 6;

    for (int nid = wave0; nid < n; nid += nw) {
        const int s = __builtin_amdgcn_readfirstlane(row_ofs[nid]);
        const int e = __builtin_amdgcn_readfirstlane(row_ofs[nid + 1]);
        float4 acc0 = make_float4(0.f, 0.f, 0.f, 0.f);
        float4 acc1 = make_float4(0.f, 0.f, 0.f, 0.f);
        for (int c = s; c < e; c += 64) {
            int rem = e - c;
            int cnt = rem < 64 ? rem : 64;
            int vi = (lane < cnt) ? csr[c + lane] : 0;
            for (int t = 0; t < cnt; t += 8) {
                int r0 = t + g;
                int r1 = t + 4 + g;
                int cl = cnt - 1;
                int i0 = __shfl(vi, r0 < cl ? r0 : cl);
                int i1 = __shfl(vi, r1 < cl ? r1 : cl);
                float4 v0 = *(const float4*)(h + (size_t)i0 * DIM + q * 4);
                float4 v1 = *(const float4*)(h + (size_t)i1 * DIM + q * 4);
                float f0 = (r0 < cnt) ? 1.f : 0.f;
                float f1 = (r1 < cnt) ? 1.f : 0.f;
                acc0.x = fmaf(v0.x, f0, acc0.x);
                acc0.y = fmaf(v0.y, f0, acc0.y);
                acc0.z = fmaf(v0.z, f0, acc0.z);
                acc0.w = fmaf(v0.w, f0, acc0.w);
                acc1.x = fmaf(v1.x, f1, acc1.x);
                acc1.y = fmaf(v1.y, f1, acc1.y);
                acc1.z = fmaf(v1.z, f1, acc1.z);
                acc1.w = fmaf(v1.w, f1, acc1.w);
            }
        }
        float4 r;
        r.x = acc0.x + acc1.x;
        r.y = acc0.y + acc1.y;
        r.z = acc0.z + acc1.z;
        r.w = acc0.w + acc1.w;
        r.x += __shfl_xor(r.x, 16);
        r.y += __shfl_xor(r.y, 16);
        r.z += __shfl_xor(r.z, 16);
        r.w += __shfl_xor(r.w, 16);
        r.x += __shfl_xor(r.x, 32);
        r.y += __shfl_xor(r.y, 32);
        r.z += __shfl_xor(r.z, 32);
        r.w += __shfl_xor(r.w, 32);
        const float iv = invd[nid];
        if (lane < 16) {
            float4 o = make_float4(r.x * iv, r.y * iv, r.z * iv, r.w * iv);
            *(float4*)(agg + (size_t)nid * DIM + q * 4) = o;
        }
    }
}

// ---------------- dual transform ----------------
// out[n][l] = b[l] + sum_d agg[n][d]*Wl[d][l] + sum_d h[n][d]*Wr[d][l] (+h[n][l]) (+relu)
__global__ __launch_bounds__(256, 1) void transform_kernel(
    const float* __restrict__ agg, const float* __restrict__ h,
    const float* __restrict__ Wl, const float* __restrict__ Wr,
    const float* __restrict__ bias, float* __restrict__ out,
    int n, int resid, int relu) {
    const int lane = threadIdx.x & 63;

    float wl[DIM], wr[DIM];
    #pragma unroll
    for (int d = 0; d < DIM; ++d) {
        wl[d] = Wl[d * DIM + lane];
        wr[d] = Wr[d * DIM + lane];
    }
    const float bv = bias[lane];

    const int nw = (gridDim.x * blockDim.x) >> 6;
    int nid = (blockIdx.x * blockDim.x + threadIdx.x) >> 6;
    if (nid >= n) return;

    float av = agg[(size_t)nid * DIM + lane];
    float hv = h[(size_t)nid * DIM + lane];

    while (true) {
        int nxt = nid + nw;
        float avn = 0.f, hvn = 0.f;
        if (nxt < n) {
            avn = agg[(size_t)nxt * DIM + lane];
            hvn = h[(size_t)nxt * DIM + lane];
        }
        float o0 = bv, o1 = 0.f, o2 = 0.f, o3 = 0.f;
        #pragma unroll
        for (int d = 0; d < DIM; d += 2) {
            float ad0 = __int_as_float(__builtin_amdgcn_readlane(__float_as_int(av), d));
            float hd0 = __int_as_float(__builtin_amdgcn_readlane(__float_as_int(hv), d));
            float ad1 = __int_as_float(__builtin_amdgcn_readlane(__float_as_int(av), d + 1));
            float hd1 = __int_as_float(__builtin_amdgcn_readlane(__float_as_int(hv), d + 1));
            o0 += ad0 * wl[d];
            o1 += hd0 * wr[d];
            o2 += ad1 * wl[d + 1];
            o3 += hd1 * wr[d + 1];
        }
        float o = (o0 + o2) + (o1 + o3);
        if (resid) o += hv;
        if (relu) o = fmaxf(o, 0.f);
        out[(size_t)nid * DIM + lane] = o;
        if (nxt >= n) break;
        nid = nxt;
        av = avn;
        hv = hvn;
    }
}

// ---------------- launch ----------------

extern "C" void kernel_launch(void* const* d_in, const int* in_sizes, int n_in,
                              void* d_out, int out_size, void* d_ws, size_t ws_size,
                              hipStream_t stream) {
    const float* x  = (const float*)d_in[0];
    const int*   ei = (const int*)d_in[1];
    const float* Wl = (const float*)d_in[2];
    const float* Wr = (const float*)d_in[3];
    const float* b  = (const float*)d_in[4];

    int N = in_sizes[0] / DIM;
    int E = in_sizes[1] / 2;
    int L = in_sizes[2] / (DIM * DIM);
    const int* src = ei;
    const int* dst = ei + E;
    float* out_f = (float*)d_out;

    char* w = (char*)d_ws;
    size_t o = 0;
    auto carve = [&](size_t bytes) {
        void* p = w + o;
        o = (o + bytes + 255) & ~(size_t)255;
        return p;
    };
    float* aggb    = (float*)carve((size_t)N * DIM * 4);   // aggregation buffer
    float* hB      = (float*)carve((size_t)N * DIM * 4);   // ping-pong with d_out
    int*   deg     = (int*)carve((size_t)N * 4);
    int*   row_ofs = (int*)carve((size_t)(N + 1) * 4);
    int*   cursor  = (int*)carve((size_t)N * 4);
    float* invd    = (float*)carve((size_t)N * 4);
    int*   csr     = (int*)carve((size_t)E * 4);
    int    nb      = (N + SCAN_CHUNK - 1) / SCAN_CHUNK;    // 98 for N=100k (<=256 req)
    int*   bsum    = (int*)carve((size_t)nb * 4);

    int shard_sz = (N + NSHARD - 1) / NSHARD;              // 12500

    // CSR build (every call; d_ws is re-poisoned between calls)
    zero_int_kernel<<<(N + 255) / 256, 256, 0, stream>>>(deg, N);
    deg_kernel_sharded<<<FILL_CHUNKS * NSHARD, 256, 0, stream>>>(dst, deg, E, shard_sz);
    bsum_kernel<<<nb, 256, 0, stream>>>(deg, bsum, N);
    bscan_kernel<<<1, 256, 0, stream>>>(bsum, nb, row_ofs, N);
    chunk_scan_kernel<<<nb, 256, 0, stream>>>(deg, bsum, row_ofs, cursor, invd, N);
    fill_kernel_sharded<<<FILL_CHUNKS * NSHARD, 256, 0, stream>>>(src, dst, cursor, csr, E, shard_sz);

    const float* hcur = x;
    for (int i = 0; i < L; ++i) {
        // Within-probe A/B: even layers run v1 (control), odd layers v2 (float4).
        if (i & 1)
            agg_kernel_v2<<<4096, 256, 0, stream>>>(hcur, row_ofs, csr, invd, aggb, N);
        else
            agg_kernel_v1<<<4096, 256, 0, stream>>>(hcur, row_ofs, csr, invd, aggb, N);

        int relu  = (i < L - 1) ? 1 : 0;
        int resid = (i > 0 && i < L - 1) ? 1 : 0;
        float* outp;
        if (i == L - 1) {
            outp = (hcur != out_f) ? out_f : hB;   // final layer -> d_out if safe
        } else {
            outp = (hcur == out_f) ? hB : out_f;   // ping-pong, never in-place
        }
        transform_kernel<<<1024, 256, 0, stream>>>(
            aggb, hcur, Wl + (size_t)i * DIM * DIM, Wr + (size_t)i * DIM * DIM,
            b + (size_t)i * DIM, outp, N, resid, relu);

        if (i == L - 1 && outp != out_f)           // generic-L safety net
            (void)hipMemcpyAsync(out_f, outp, (size_t)N * DIM * 4,
                                 hipMemcpyDeviceToDevice, stream);
        hcur = outp;
    }
}